// Round 5
// baseline (469.805 us; speedup 1.0000x reference)
//
#include <hip/hip_runtime.h>
#include <stdint.h>
#include <stddef.h>

typedef float    f32x4 __attribute__((ext_vector_type(4)));
typedef float    f32x2 __attribute__((ext_vector_type(2)));
typedef _Float16 f16x4 __attribute__((ext_vector_type(4)));
typedef _Float16 f16x8 __attribute__((ext_vector_type(8)));

#define HH 96
#define RPB 32       // rows per block: 16 "P" + 16 "Q", role-split across waves
#define OCT 136      // h1 A-layout oct stride in halves (272 B)

// 16-lane-row sum via DPP (VALU, no DS): xor1, xor2 (quad_perm), ror4, ror8
#define DPP_ADD(v, ctrl) \
    ((v) + __builtin_bit_cast(float, __builtin_amdgcn_update_dpp( \
        0, __builtin_bit_cast(int, (v)), (ctrl), 0xF, 0xF, true)))

struct SState { float A, S, B, C, SS, AD; };

__device__ __forceinline__ float scan_update(
    SState& st, float psum, float dem, f32x2 nz, f32x4 tb,
    float b3s, float lam, float per_step, bool last)
{
    float a_ml   = fmaxf(psum + b3s, 0.0f);
    float a_prior = fminf(fmaxf(st.S + dem, 0.0f) * 1.25f, 10.0f);
    float sgn    = (a_ml < a_prior) ? 1.0f : -1.0f;
    float a_out  = fmaf(fmaxf(fabsf(a_ml - a_prior) - st.B * tb[2], 0.0f), sgn, a_ml);
    float ns     = fminf(fmaxf(st.S * (1.0f - nz[1]) + dem - (0.8f + nz[0]) * a_out, 0.0f), 15.0f);
    float c_cost = fmaf(fmaf(0.1f, ns, 1.0f), ns, 2.0f);
    float ad_new = fabsf(a_out - a_prior);
    float cum_dv = fmaf(2.0f, ad_new, 0.375f * st.SS);
    float c_prior = fmaxf(2.0f, c_cost - cum_dv);
    float cum_c_new = st.C + (1.0f + lam) * c_prior - c_cost;
    float T      = fmaf(0.25f, st.SS, ad_new);
    float cum_dg = tb[0] * T;
    float bgt_if = fmaxf(fmaxf(st.B + per_step - ad_new * tb[1], 0.0f),
                         cum_c_new - cum_dg + tb[3]);
    float bgt_else = fmaxf(st.B + per_step - st.AD * tb[1], 0.0f);
    if (last) { st.B = bgt_else; }
    else      { st.B = bgt_if; st.C = cum_c_new; }
    st.SS = T; st.AD = ad_new; st.A = a_out; st.S = ns;
    return a_out;
}

__device__ __forceinline__ void phaseA(
    _Float16* h1, const f32x4& f, const SState& st,
    const f16x8* w1A, int lq, int h1wbase)
{
    f16x8 xB = {};
    if (lq == 0) {
        xB[0]=(_Float16)f[0]; xB[1]=(_Float16)f[1];
        xB[2]=(_Float16)f[2]; xB[3]=(_Float16)f[3];
        xB[4]=(_Float16)st.A; xB[5]=(_Float16)st.S;
        xB[6]=(_Float16)1.0f;
    }
    #pragma unroll
    for (int tt = 0; tt < 2; ++tt) {
        f32x4 g = {0.f,0.f,0.f,0.f};
        g = __builtin_amdgcn_mfma_f32_16x16x32_f16(w1A[tt], xB, g, 0, 0, 0);
        f16x4 hv;
        #pragma unroll
        for (int r = 0; r < 4; ++r) hv[r] = (_Float16)fmaxf(g[r], 0.0f);
        *(f16x4*)&h1[h1wbase + tt*(2*OCT)] = hv;    // ds_write_b64
    }
}

__launch_bounds__(1024, 4)
__global__ void policy_scan_kernel(
    const float* __restrict__ policy,     // (B,96,4)
    const float* __restrict__ noiseT,     // (B,96)
    const float* __restrict__ noiseD,     // (B,96)
    const float* __restrict__ action_pre, // (B,)
    const float* __restrict__ state_pre,  // (B,)
    const float* __restrict__ Lambda1,    // (1,)
    const float* __restrict__ Budget1,    // (1,)
    const float* __restrict__ W1,         // (256,6)
    const float* __restrict__ b1,         // (256,)
    const float* __restrict__ W2,         // (256,256)
    const float* __restrict__ b2,         // (256,)
    const float* __restrict__ W3,         // (256,)
    const float* __restrict__ b3,         // (1,)
    float* __restrict__ out)              // (B,96)
{
    __shared__ __attribute__((aligned(16))) _Float16 h1P[32*OCT];   // 8704 B
    __shared__ __attribute__((aligned(16))) _Float16 h1Q[32*OCT];   // 8704 B
    __shared__ __attribute__((aligned(16))) float    partP[16*8];   // [m][wid8] 512 B
    __shared__ __attribute__((aligned(16))) float    partQ[16*8];   // 512 B
    __shared__ __attribute__((aligned(16))) float    tblLDS[HH*4];  // 1536 B

    const int tid   = threadIdx.x;          // 0..1023
    const int wv    = tid >> 6;             // 0..15
    const int roleQ = (wv >> 2) & 1;        // waves 0-3,8-11 = P; 4-7,12-15 = Q
    const int wid8  = (wv & 3) | ((wv >> 3) << 2);   // 0..7 within role
    const int lane  = tid & 63;
    const int l16   = lane & 15;
    const int lq    = lane >> 4;            // 0..3
    const int r0    = blockIdx.x * RPB;
    const int rbase = r0 + roleQ * 16;

    const float lam  = Lambda1[0];
    const float budH = Budget1[0] * (1.0f/96.0f);
    const float b3s  = b3[0];
    const float per_step = lam * 2.0f + budH;
    if (tid < HH) {
        float e  = __builtin_exp2f(-2.0f * (float)(95 - tid));
        float ft = 0.5f * (1.0f - e);
        float G  = 2.0f + ft;
        *(f32x4*)&tblLDS[tid*4] = f32x4{ft, G, 1.0f/G, lam*2.0f + budH*((float)tid + 2.0f)};
    }

    // ---- W2 -> fp16 B-frags: 2 n-tiles/wave (64 VGPR) ----
    // tile tt covers n = wid8*32 + tt*16 + l16 ; k = kc*32 + lq*8 + j
    f16x8 bfr[2][8];
    float b2v[2], w3v[2];
    #pragma unroll
    for (int tt = 0; tt < 2; ++tt) {
        const int n = wid8*32 + tt*16 + l16;
        const float* wrow = W2 + (size_t)n * 256;
        #pragma unroll
        for (int kc = 0; kc < 8; ++kc) {
            const int k0 = kc*32 + lq*8;
            f32x4 u0 = *(const f32x4*)(wrow + k0);
            f32x4 u1 = *(const f32x4*)(wrow + k0 + 4);
            f16x8 v;
            v[0]=(_Float16)u0[0]; v[1]=(_Float16)u0[1]; v[2]=(_Float16)u0[2]; v[3]=(_Float16)u0[3];
            v[4]=(_Float16)u1[0]; v[5]=(_Float16)u1[1]; v[6]=(_Float16)u1[2]; v[7]=(_Float16)u1[3];
            bfr[tt][kc] = v;
        }
        b2v[tt] = b2[n];
        w3v[tt] = W3[n];
    }

    // ---- W1 as MFMA A-frags (bias folded at k=6) ----
    f16x8 w1A[2];
    #pragma unroll
    for (int tt = 0; tt < 2; ++tt) {
        f16x8 w = {};
        if (lq == 0) {
            const int nn = wid8*32 + tt*16 + l16;
            #pragma unroll
            for (int j = 0; j < 6; ++j) w[j] = (_Float16)W1[nn*6 + j];
            w[6] = (_Float16)b1[nn];
        }
        w1A[tt] = w;
    }

    // h1 write: value (tt,r) -> k = wid8*32+tt*16+lq*4+r, m = l16
    const int h1wbase = (wid8*4 + (lq>>1))*OCT + l16*8 + (lq&1)*4;
    const int h1rbase = lq*OCT + l16*8;          // + kc*(4*OCT)

    // ---- per-row inputs (row rbase+l16, replicated across lq) ----
    const float* fRow = policy + (size_t)(rbase + l16) * (HH*4);
    const float* tRow = noiseT + (size_t)(rbase + l16) * HH;
    const float* dRow = noiseD + (size_t)(rbase + l16) * HH;

    SState st = { action_pre[rbase + l16], state_pre[rbase + l16],
                  per_step, 0.f, 0.f, 0.f };

    f32x4 fCur  = *(const f32x4*)(fRow);
    f32x2 nzCur = { tRow[0], dRow[0] };
    f32x4 fNxt;
    f32x2 nzNxt;
    float demPrev = 0.f;
    f32x2 nzPrev  = {0.f, 0.f};
    f32x4 tbPrev  = {0.f, 0.f, 0.f, 0.f};

    // ---- prologue: P stages h1P(0) ----
    if (!roleQ) phaseA(h1P, fCur, st, w1A, lq, h1wbase);
    __syncthreads();   // b1(0): h1P(0) ready; tbl ready

    #pragma unroll 1
    for (int t = 0; t < HH; ++t) {
        const int tn = (t < HH-1) ? t+1 : HH-1;
        if (!roleQ) {
            // ---- P half-1: B(t) + C(t); prefetch t+1 (hides under MFMA) ----
            f32x4 a0 = f32x4{b2v[0],b2v[0],b2v[0],b2v[0]};
            f32x4 a1 = f32x4{b2v[1],b2v[1],b2v[1],b2v[1]};
            #pragma unroll
            for (int kc = 0; kc < 8; ++kc) {
                f16x8 a = *(const f16x8*)&h1P[h1rbase + kc*(4*OCT)];
                a0 = __builtin_amdgcn_mfma_f32_16x16x32_f16(a, bfr[0][kc], a0, 0, 0, 0);
                a1 = __builtin_amdgcn_mfma_f32_16x16x32_f16(a, bfr[1][kc], a1, 0, 0, 0);
            }
            fNxt  = *(const f32x4*)(fRow + tn*4);
            nzNxt = f32x2{ tRow[tn], dRow[tn] };
            #pragma unroll
            for (int r = 0; r < 4; ++r) {
                float v = fmaf(w3v[0], fmaxf(a0[r], 0.0f), w3v[1] * fmaxf(a1[r], 0.0f));
                v = DPP_ADD(v, 0xB1); v = DPP_ADD(v, 0x4E);
                v = DPP_ADD(v, 0x124); v = DPP_ADD(v, 0x128);
                if (l16 == 0) partP[(lq*4 + r)*8 + wid8] = v;
            }
        } else {
            // ---- Q half-1: D(t-1) + A(t) ----
            const f32x4 tbCur = *(const f32x4*)&tblLDS[t*4];
            if (t > 0) {
                f32x4 q0 = *(const f32x4*)&partQ[l16*8];
                f32x4 q1 = *(const f32x4*)&partQ[l16*8 + 4];
                float psum = ((q0[0]+q0[1]) + (q0[2]+q0[3]))
                           + ((q1[0]+q1[1]) + (q1[2]+q1[3]));
                float aQ = scan_update(st, psum, demPrev, nzPrev, tbPrev,
                                       b3s, lam, per_step, false);
                if (wid8 == 0 && lane < 16) out[(size_t)(rbase + lane)*HH + (t-1)] = aQ;
            }
            phaseA(h1Q, fCur, st, w1A, lq, h1wbase);
            demPrev = fCur[0]; nzPrev = nzCur; tbPrev = tbCur;
        }
        __syncthreads();   // b2: partP(t) ready; h1Q(t) ready

        if (!roleQ) {
            // ---- P half-2: D(t) + A(t+1) ----
            const f32x4 tb = *(const f32x4*)&tblLDS[t*4];
            f32x4 q0 = *(const f32x4*)&partP[l16*8];
            f32x4 q1 = *(const f32x4*)&partP[l16*8 + 4];
            float psum = ((q0[0]+q0[1]) + (q0[2]+q0[3]))
                       + ((q1[0]+q1[1]) + (q1[2]+q1[3]));
            float aP = scan_update(st, psum, fCur[0], nzCur, tb,
                                   b3s, lam, per_step, t == HH-1);
            if (wid8 == 0 && lane < 16) out[(size_t)(rbase + lane)*HH + t] = aP;
            if (t < HH-1) phaseA(h1P, fNxt, st, w1A, lq, h1wbase);
            fCur = fNxt; nzCur = nzNxt;
        } else {
            // ---- Q half-2: B(t) + C(t); prefetch t+1 ----
            f32x4 a0 = f32x4{b2v[0],b2v[0],b2v[0],b2v[0]};
            f32x4 a1 = f32x4{b2v[1],b2v[1],b2v[1],b2v[1]};
            #pragma unroll
            for (int kc = 0; kc < 8; ++kc) {
                f16x8 a = *(const f16x8*)&h1Q[h1rbase + kc*(4*OCT)];
                a0 = __builtin_amdgcn_mfma_f32_16x16x32_f16(a, bfr[0][kc], a0, 0, 0, 0);
                a1 = __builtin_amdgcn_mfma_f32_16x16x32_f16(a, bfr[1][kc], a1, 0, 0, 0);
            }
            fNxt  = *(const f32x4*)(fRow + tn*4);
            nzNxt = f32x2{ tRow[tn], dRow[tn] };
            #pragma unroll
            for (int r = 0; r < 4; ++r) {
                float v = fmaf(w3v[0], fmaxf(a0[r], 0.0f), w3v[1] * fmaxf(a1[r], 0.0f));
                v = DPP_ADD(v, 0xB1); v = DPP_ADD(v, 0x4E);
                v = DPP_ADD(v, 0x124); v = DPP_ADD(v, 0x128);
                if (l16 == 0) partQ[(lq*4 + r)*8 + wid8] = v;
            }
            fCur = fNxt; nzCur = nzNxt;
        }
        __syncthreads();   // b1: h1P(t+1) ready; partQ(t) ready
    }

    // ---- epilogue: Q: D(95) ----
    if (roleQ) {
        f32x4 q0 = *(const f32x4*)&partQ[l16*8];
        f32x4 q1 = *(const f32x4*)&partQ[l16*8 + 4];
        float psum = ((q0[0]+q0[1]) + (q0[2]+q0[3]))
                   + ((q1[0]+q1[1]) + (q1[2]+q1[3]));
        float aQ = scan_update(st, psum, demPrev, nzPrev, tbPrev,
                               b3s, lam, per_step, true);
        if (wid8 == 0 && lane < 16) out[(size_t)(rbase + lane)*HH + (HH-1)] = aQ;
    }
}

extern "C" void kernel_launch(void* const* d_in, const int* in_sizes, int n_in,
                              void* d_out, int out_size, void* d_ws, size_t ws_size,
                              hipStream_t stream) {
    policy_scan_kernel<<<dim3(8192 / RPB), dim3(1024), 0, stream>>>(
        (const float*)d_in[0],  // policy_in_c
        (const float*)d_in[1],  // trans_noise
        (const float*)d_in[2],  // demand_noise
        (const float*)d_in[3],  // action_pre
        (const float*)d_in[4],  // state_pre
        (const float*)d_in[5],  // Lambda
        (const float*)d_in[6],  // Budget
        (const float*)d_in[7],  // W1
        (const float*)d_in[8],  // b1
        (const float*)d_in[9],  // W2
        (const float*)d_in[10], // b2
        (const float*)d_in[11], // W3
        (const float*)d_in[12], // b3
        (float*)d_out);
}

// Round 6
// 249.330 us; speedup vs baseline: 1.8843x; 1.8843x over previous
//
#include <hip/hip_runtime.h>
#include <stdint.h>
#include <stddef.h>

typedef float    f32x4 __attribute__((ext_vector_type(4)));
typedef float    f32x2 __attribute__((ext_vector_type(2)));
typedef _Float16 f16x4 __attribute__((ext_vector_type(4)));
typedef _Float16 f16x8 __attribute__((ext_vector_type(8)));

#define HH 96
#define RPB 32       // rows per block: 16 "P" (waves 0-3) + 16 "Q" (waves 4-7)
#define OCT 136      // h1 A-layout oct stride in halves (272 B)
#define OSTR 100     // outLDS row stride in dwords

// 16-lane-row sum via DPP (VALU, no DS): xor1, xor2 (quad_perm), ror4, ror8
#define DPP_ADD(v, ctrl) \
    ((v) + __builtin_bit_cast(float, __builtin_amdgcn_update_dpp( \
        0, __builtin_bit_cast(int, (v)), (ctrl), 0xF, 0xF, true)))

struct SState { float A, S, B, C, SS, AD; };

__device__ __forceinline__ float scan_update(
    SState& st, float psum, float dem, f32x2 nz, f32x4 tb,
    float b3s, float lam, float per_step, bool last)
{
    float a_ml   = fmaxf(psum + b3s, 0.0f);
    float a_prior = fminf(fmaxf(st.S + dem, 0.0f) * 1.25f, 10.0f);
    float sgn    = (a_ml < a_prior) ? 1.0f : -1.0f;
    float a_out  = fmaf(fmaxf(fabsf(a_ml - a_prior) - st.B * tb[2], 0.0f), sgn, a_ml);
    float ns     = fminf(fmaxf(st.S * (1.0f - nz[1]) + dem - (0.8f + nz[0]) * a_out, 0.0f), 15.0f);
    float c_cost = fmaf(fmaf(0.1f, ns, 1.0f), ns, 2.0f);
    float ad_new = fabsf(a_out - a_prior);
    float cum_dv = fmaf(2.0f, ad_new, 0.375f * st.SS);
    float c_prior = fmaxf(2.0f, c_cost - cum_dv);
    float cum_c_new = st.C + (1.0f + lam) * c_prior - c_cost;
    float T      = fmaf(0.25f, st.SS, ad_new);
    float cum_dg = tb[0] * T;
    float bgt_if = fmaxf(fmaxf(st.B + per_step - ad_new * tb[1], 0.0f),
                         cum_c_new - cum_dg + tb[3]);
    float bgt_else = fmaxf(st.B + per_step - st.AD * tb[1], 0.0f);
    if (last) { st.B = bgt_else; }
    else      { st.B = bgt_if; st.C = cum_c_new; }
    st.SS = T; st.AD = ad_new; st.A = a_out; st.S = ns;
    return a_out;
}

// Layer-1: 4 MFMA -> relu -> pack -> h1 (A-frag layout for phase B)
__device__ __forceinline__ void phaseA(
    _Float16* h1, const f32x4& f, const SState& st,
    const f16x8* w1A, int lq, int h1wbase)
{
    f16x8 xB = {};
    if (lq == 0) {
        xB[0]=(_Float16)f[0]; xB[1]=(_Float16)f[1];
        xB[2]=(_Float16)f[2]; xB[3]=(_Float16)f[3];
        xB[4]=(_Float16)st.A; xB[5]=(_Float16)st.S;
        xB[6]=(_Float16)1.0f;
    }
    #pragma unroll
    for (int tt = 0; tt < 4; ++tt) {
        f32x4 g = {0.f,0.f,0.f,0.f};
        g = __builtin_amdgcn_mfma_f32_16x16x32_f16(w1A[tt], xB, g, 0, 0, 0);
        f16x4 hv;
        #pragma unroll
        for (int r = 0; r < 4; ++r) hv[r] = (_Float16)fmaxf(g[r], 0.0f);
        *(f16x4*)&h1[h1wbase + tt*(2*OCT)] = hv;    // ds_write_b64
    }
}

__launch_bounds__(512, 2)
__global__ void policy_scan_kernel(
    const float* __restrict__ policy,     // (B,96,4)
    const float* __restrict__ noiseT,     // (B,96)
    const float* __restrict__ noiseD,     // (B,96)
    const float* __restrict__ action_pre, // (B,)
    const float* __restrict__ state_pre,  // (B,)
    const float* __restrict__ Lambda1,    // (1,)
    const float* __restrict__ Budget1,    // (1,)
    const float* __restrict__ W1,         // (256,6)
    const float* __restrict__ b1,         // (256,)
    const float* __restrict__ W2,         // (256,256)
    const float* __restrict__ b2,         // (256,)
    const float* __restrict__ W3,         // (256,)
    const float* __restrict__ b3,         // (1,)
    float* __restrict__ out)              // (B,96)
{
    __shared__ __attribute__((aligned(16))) _Float16 h1P[32*OCT];     // 8704 B
    __shared__ __attribute__((aligned(16))) _Float16 h1Q[32*OCT];     // 8704 B
    __shared__ __attribute__((aligned(16))) float    partP[16*4];     // [m][wid4] 256 B
    __shared__ __attribute__((aligned(16))) float    partQ[16*4];     // 256 B
    __shared__ __attribute__((aligned(16))) float    tblLDS[HH*4];    // 1536 B
    __shared__ __attribute__((aligned(16))) float    outLDS[RPB*OSTR];// 12800 B

    const int tid   = threadIdx.x;          // 0..511
    const int wv    = tid >> 6;             // 0..7
    const int roleQ = (wv >> 2) & 1;        // waves 0-3 = P; 4-7 = Q (wv%4 -> SIMD: 1P+1Q each)
    const int wid4  = wv & 3;               // 0..3 within role
    const int lane  = tid & 63;
    const int l16   = lane & 15;
    const int lq    = lane >> 4;            // 0..3
    const int r0    = blockIdx.x * RPB;
    const int rbase = r0 + roleQ * 16;

    const float lam  = Lambda1[0];
    const float budH = Budget1[0] * (1.0f/96.0f);
    const float b3s  = b3[0];
    const float per_step = lam * 2.0f + budH;
    if (tid < HH) {
        float e  = __builtin_exp2f(-2.0f * (float)(95 - tid));
        float ft = 0.5f * (1.0f - e);
        float G  = 2.0f + ft;
        *(f32x4*)&tblLDS[tid*4] = f32x4{ft, G, 1.0f/G, lam*2.0f + budH*((float)tid + 2.0f)};
    }

    // ---- W2 -> fp16 B-frags: 4 n-tiles/wave (64 VGPR), baseline-identical ----
    f16x8 bfr[4][8];
    float b2v[4], w3v[4];
    #pragma unroll
    for (int tt = 0; tt < 4; ++tt) {
        const int n = wid4*64 + tt*16 + l16;
        const float* wrow = W2 + (size_t)n * 256;
        #pragma unroll
        for (int kc = 0; kc < 8; ++kc) {
            const int k0 = kc*32 + lq*8;
            f32x4 u0 = *(const f32x4*)(wrow + k0);
            f32x4 u1 = *(const f32x4*)(wrow + k0 + 4);
            f16x8 v;
            v[0]=(_Float16)u0[0]; v[1]=(_Float16)u0[1]; v[2]=(_Float16)u0[2]; v[3]=(_Float16)u0[3];
            v[4]=(_Float16)u1[0]; v[5]=(_Float16)u1[1]; v[6]=(_Float16)u1[2]; v[7]=(_Float16)u1[3];
            bfr[tt][kc] = v;
        }
        b2v[tt] = b2[n];
        w3v[tt] = W3[n];
    }

    // ---- W1 as MFMA A-frags (bias folded at k=6) ----
    f16x8 w1A[4];
    #pragma unroll
    for (int tt = 0; tt < 4; ++tt) {
        f16x8 w = {};
        if (lq == 0) {
            const int nn = wid4*64 + tt*16 + l16;
            #pragma unroll
            for (int j = 0; j < 6; ++j) w[j] = (_Float16)W1[nn*6 + j];
            w[6] = (_Float16)b1[nn];
        }
        w1A[tt] = w;
    }

    // h1 write: value (tt,r) -> k = wid4*64+tt*16+lq*4+r, m = l16
    const int h1wbase = (wid4*8 + (lq>>1))*OCT + l16*8 + (lq&1)*4;
    const int h1rbase = lq*OCT + l16*8;          // + kc*(4*OCT)

    // ---- per-row inputs (row rbase+l16, replicated across lq) ----
    const float* fRow = policy + (size_t)(rbase + l16) * (HH*4);
    const float* tRow = noiseT + (size_t)(rbase + l16) * HH;
    const float* dRow = noiseD + (size_t)(rbase + l16) * HH;

    SState st = { action_pre[rbase + l16], state_pre[rbase + l16],
                  per_step, 0.f, 0.f, 0.f };

    f32x4 fCur  = *(const f32x4*)(fRow);
    f32x2 nzCur = { tRow[0], dRow[0] };
    f32x4 fNxt;
    f32x2 nzNxt;
    float demPrev = 0.f;
    f32x2 nzPrev  = {0.f, 0.f};
    f32x4 tbPrev  = {0.f, 0.f, 0.f, 0.f};

    // ---- prologue: P stages h1P(0) ----
    if (!roleQ) phaseA(h1P, fCur, st, w1A, lq, h1wbase);
    __syncthreads();   // h1P(0) ready; tbl ready

    #pragma unroll 1
    for (int t = 0; t < HH; ++t) {
        const int tn = (t < HH-1) ? t+1 : HH-1;
        if (!roleQ) {
            // ---- P half-1: B(t)+C(t); prefetch t+1 under the MFMA burst ----
            f32x4 acc[4];
            #pragma unroll
            for (int tt = 0; tt < 4; ++tt) acc[tt] = f32x4{b2v[tt],b2v[tt],b2v[tt],b2v[tt]};
            #pragma unroll
            for (int kc = 0; kc < 8; ++kc) {
                f16x8 a = *(const f16x8*)&h1P[h1rbase + kc*(4*OCT)];
                #pragma unroll
                for (int tt = 0; tt < 4; ++tt)
                    acc[tt] = __builtin_amdgcn_mfma_f32_16x16x32_f16(a, bfr[tt][kc], acc[tt], 0, 0, 0);
            }
            fNxt  = *(const f32x4*)(fRow + tn*4);
            nzNxt = f32x2{ tRow[tn], dRow[tn] };
            #pragma unroll
            for (int r = 0; r < 4; ++r) {
                float s0 = fmaf(w3v[0], fmaxf(acc[0][r], 0.0f), w3v[1] * fmaxf(acc[1][r], 0.0f));
                float s1 = fmaf(w3v[2], fmaxf(acc[2][r], 0.0f), w3v[3] * fmaxf(acc[3][r], 0.0f));
                float v = s0 + s1;
                v = DPP_ADD(v, 0xB1); v = DPP_ADD(v, 0x4E);
                v = DPP_ADD(v, 0x124); v = DPP_ADD(v, 0x128);
                if (l16 == 0) partP[(lq*4 + r)*4 + wid4] = v;
            }
        } else {
            // ---- Q half-1: D(t-1) + A(t) ----
            const f32x4 tbCur = *(const f32x4*)&tblLDS[t*4];
            if (t > 0) {
                f32x4 q = *(const f32x4*)&partQ[l16*4];
                float psum = (q[0] + q[1]) + (q[2] + q[3]);
                float aQ = scan_update(st, psum, demPrev, nzPrev, tbPrev,
                                       b3s, lam, per_step, false);
                if (wid4 == 0 && lane < 16) outLDS[(16 + lane)*OSTR + (t-1)] = aQ;
            }
            phaseA(h1Q, fCur, st, w1A, lq, h1wbase);
            demPrev = fCur[0]; nzPrev = nzCur; tbPrev = tbCur;
        }
        __syncthreads();   // partP(t) ready; h1Q(t) ready

        if (!roleQ) {
            // ---- P half-2: D(t) + A(t+1) ----
            const f32x4 tb = *(const f32x4*)&tblLDS[t*4];
            f32x4 q = *(const f32x4*)&partP[l16*4];
            float psum = (q[0] + q[1]) + (q[2] + q[3]);
            float aP = scan_update(st, psum, fCur[0], nzCur, tb,
                                   b3s, lam, per_step, t == HH-1);
            if (wid4 == 0 && lane < 16) outLDS[lane*OSTR + t] = aP;
            if (t < HH-1) phaseA(h1P, fNxt, st, w1A, lq, h1wbase);
            fCur = fNxt; nzCur = nzNxt;
        } else {
            // ---- Q half-2: B(t)+C(t); prefetch t+1 ----
            f32x4 acc[4];
            #pragma unroll
            for (int tt = 0; tt < 4; ++tt) acc[tt] = f32x4{b2v[tt],b2v[tt],b2v[tt],b2v[tt]};
            #pragma unroll
            for (int kc = 0; kc < 8; ++kc) {
                f16x8 a = *(const f16x8*)&h1Q[h1rbase + kc*(4*OCT)];
                #pragma unroll
                for (int tt = 0; tt < 4; ++tt)
                    acc[tt] = __builtin_amdgcn_mfma_f32_16x16x32_f16(a, bfr[tt][kc], acc[tt], 0, 0, 0);
            }
            fNxt  = *(const f32x4*)(fRow + tn*4);
            nzNxt = f32x2{ tRow[tn], dRow[tn] };
            #pragma unroll
            for (int r = 0; r < 4; ++r) {
                float s0 = fmaf(w3v[0], fmaxf(acc[0][r], 0.0f), w3v[1] * fmaxf(acc[1][r], 0.0f));
                float s1 = fmaf(w3v[2], fmaxf(acc[2][r], 0.0f), w3v[3] * fmaxf(acc[3][r], 0.0f));
                float v = s0 + s1;
                v = DPP_ADD(v, 0xB1); v = DPP_ADD(v, 0x4E);
                v = DPP_ADD(v, 0x124); v = DPP_ADD(v, 0x128);
                if (l16 == 0) partQ[(lq*4 + r)*4 + wid4] = v;
            }
            fCur = fNxt; nzCur = nzNxt;
        }
        __syncthreads();   // h1P(t+1) ready; partQ(t) ready
    }

    // ---- epilogue: Q: D(95) ----
    if (roleQ) {
        f32x4 q = *(const f32x4*)&partQ[l16*4];
        float psum = (q[0] + q[1]) + (q[2] + q[3]);
        float aQ = scan_update(st, psum, demPrev, nzPrev, tbPrev,
                               b3s, lam, per_step, true);
        if (wid4 == 0 && lane < 16) outLDS[(16 + lane)*OSTR + (HH-1)] = aQ;
    }

    // ---- coalesced output dump: 32 rows x 96 = 3072 dwords, 512 threads ----
    __syncthreads();
    float* oslice = out + (size_t)r0 * HH;
    #pragma unroll
    for (int i = 0; i < 3; ++i) {
        int idx = (i*512 + tid) * 2;               // 3072 dwords total
        int row = idx / 96, c = idx - row*96;      // pairs never straddle rows (96 even)
        f32x2 v = { outLDS[row*OSTR + c], outLDS[row*OSTR + c + 1] };
        *(f32x2*)&oslice[idx] = v;
    }
}

extern "C" void kernel_launch(void* const* d_in, const int* in_sizes, int n_in,
                              void* d_out, int out_size, void* d_ws, size_t ws_size,
                              hipStream_t stream) {
    policy_scan_kernel<<<dim3(8192 / RPB), dim3(512), 0, stream>>>(
        (const float*)d_in[0],  // policy_in_c
        (const float*)d_in[1],  // trans_noise
        (const float*)d_in[2],  // demand_noise
        (const float*)d_in[3],  // action_pre
        (const float*)d_in[4],  // state_pre
        (const float*)d_in[5],  // Lambda
        (const float*)d_in[6],  // Budget
        (const float*)d_in[7],  // W1
        (const float*)d_in[8],  // b1
        (const float*)d_in[9],  // W2
        (const float*)d_in[10], // b2
        (const float*)d_in[11], // W3
        (const float*)d_in[12], // b3
        (float*)d_out);
}

// Round 7
// 240.597 us; speedup vs baseline: 1.9527x; 1.0363x over previous
//
#include <hip/hip_runtime.h>
#include <stdint.h>
#include <stddef.h>

typedef float    f32x4 __attribute__((ext_vector_type(4)));
typedef float    f32x2 __attribute__((ext_vector_type(2)));
typedef _Float16 f16x4 __attribute__((ext_vector_type(4)));
typedef _Float16 f16x8 __attribute__((ext_vector_type(8)));

#define HH 96
#define RPB 32       // rows per block: 16 "P" (waves 0-3) + 16 "Q" (waves 4-7)
#define OCT 136      // h1 A-layout oct stride in halves (272 B)
#define NSTR 64      // noiseTD per-t stride in dwords (32 rows x float2)
#define OSTR 100     // outLDS row stride in dwords

// 16-lane-row sum via DPP (VALU, no DS): xor1, xor2 (quad_perm), ror4, ror8
#define DPP_ADD(v, ctrl) \
    ((v) + __builtin_bit_cast(float, __builtin_amdgcn_update_dpp( \
        0, __builtin_bit_cast(int, (v)), (ctrl), 0xF, 0xF, true)))

struct SState { float A, S, B, C, SS, AD; };

__device__ __forceinline__ float scan_update(
    SState& st, float psum, float dem, f32x2 nz, f32x4 tb,
    float b3s, float lam, float per_step, bool last)
{
    float a_ml   = fmaxf(psum + b3s, 0.0f);
    float a_prior = fminf(fmaxf(st.S + dem, 0.0f) * 1.25f, 10.0f);
    float sgn    = (a_ml < a_prior) ? 1.0f : -1.0f;
    float a_out  = fmaf(fmaxf(fabsf(a_ml - a_prior) - st.B * tb[2], 0.0f), sgn, a_ml);
    float ns     = fminf(fmaxf(st.S * (1.0f - nz[1]) + dem - (0.8f + nz[0]) * a_out, 0.0f), 15.0f);
    float c_cost = fmaf(fmaf(0.1f, ns, 1.0f), ns, 2.0f);
    float ad_new = fabsf(a_out - a_prior);
    float cum_dv = fmaf(2.0f, ad_new, 0.375f * st.SS);
    float c_prior = fmaxf(2.0f, c_cost - cum_dv);
    float cum_c_new = st.C + (1.0f + lam) * c_prior - c_cost;
    float T      = fmaf(0.25f, st.SS, ad_new);
    float cum_dg = tb[0] * T;
    float bgt_if = fmaxf(fmaxf(st.B + per_step - ad_new * tb[1], 0.0f),
                         cum_c_new - cum_dg + tb[3]);
    float bgt_else = fmaxf(st.B + per_step - st.AD * tb[1], 0.0f);
    if (last) { st.B = bgt_else; }
    else      { st.B = bgt_if; st.C = cum_c_new; }
    st.SS = T; st.AD = ad_new; st.A = a_out; st.S = ns;
    return a_out;
}

// Layer-1: 4 MFMA -> relu -> pack -> h1 (A-frag layout for phase B)
__device__ __forceinline__ void phaseA(
    _Float16* h1, const f32x4& f, const SState& st,
    const f16x8* w1A, int lq, int h1wbase)
{
    f16x8 xB = {};
    if (lq == 0) {
        xB[0]=(_Float16)f[0]; xB[1]=(_Float16)f[1];
        xB[2]=(_Float16)f[2]; xB[3]=(_Float16)f[3];
        xB[4]=(_Float16)st.A; xB[5]=(_Float16)st.S;
        xB[6]=(_Float16)1.0f;
    }
    #pragma unroll
    for (int tt = 0; tt < 4; ++tt) {
        f32x4 g = {0.f,0.f,0.f,0.f};
        g = __builtin_amdgcn_mfma_f32_16x16x32_f16(w1A[tt], xB, g, 0, 0, 0);
        f16x4 hv;
        #pragma unroll
        for (int r = 0; r < 4; ++r) hv[r] = (_Float16)fmaxf(g[r], 0.0f);
        *(f16x4*)&h1[h1wbase + tt*(2*OCT)] = hv;    // ds_write_b64
    }
}

__launch_bounds__(512, 1)
__global__ void policy_scan_kernel(
    const float* __restrict__ policy,     // (B,96,4)
    const float* __restrict__ noiseT,     // (B,96)
    const float* __restrict__ noiseD,     // (B,96)
    const float* __restrict__ action_pre, // (B,)
    const float* __restrict__ state_pre,  // (B,)
    const float* __restrict__ Lambda1,    // (1,)
    const float* __restrict__ Budget1,    // (1,)
    const float* __restrict__ W1,         // (256,6)
    const float* __restrict__ b1,         // (256,)
    const float* __restrict__ W2,         // (256,256)
    const float* __restrict__ b2,         // (256,)
    const float* __restrict__ W3,         // (256,)
    const float* __restrict__ b3,         // (1,)
    float* __restrict__ out)              // (B,96)
{
    __shared__ __attribute__((aligned(16))) float    featLDS[HH*RPB*4];  // 49152 B
    __shared__ __attribute__((aligned(16))) float    noiseTD[HH*NSTR];   // 24576 B
    __shared__ __attribute__((aligned(16))) _Float16 h1P[32*OCT];        // 8704 B
    __shared__ __attribute__((aligned(16))) _Float16 h1Q[32*OCT];        // 8704 B
    __shared__ __attribute__((aligned(16))) float    partP[16*4];        // 256 B
    __shared__ __attribute__((aligned(16))) float    partQ[16*4];        // 256 B
    __shared__ __attribute__((aligned(16))) float    tblLDS[HH*4];       // 1536 B
    __shared__ __attribute__((aligned(16))) float    outLDS[RPB*OSTR];   // 12800 B
    // total ~106 KB -> 1 block/CU (grid is 256 = 1/CU anyway)

    const int tid   = threadIdx.x;          // 0..511
    const int wv    = tid >> 6;             // 0..7
    const int roleQ = (wv >> 2) & 1;        // waves 0-3 = P; 4-7 = Q (wv%4 -> SIMD: 1P+1Q each)
    const int wid4  = wv & 3;               // 0..3 within role
    const int lane  = tid & 63;
    const int l16   = lane & 15;
    const int lq    = lane >> 4;            // 0..3
    const int r0    = blockIdx.x * RPB;
    const int rloc  = roleQ * 16 + l16;     // row within block
    const int rbase = r0 + roleQ * 16;

    // ---- stage ALL inputs to LDS upfront: ZERO global ops in the t-loop ----
    {
        const f32x4* src = (const f32x4*)(policy + (size_t)r0 * HH * 4);
        #pragma unroll
        for (int i = 0; i < 6; ++i) {
            int idx = i*512 + tid;                 // idx = row*96 + t  (3072 total)
            int row = idx / 96, t = idx - row*96;
            *(f32x4*)&featLDS[(t*RPB + row)*4] = src[idx];
        }
        const float* s1 = noiseT + (size_t)r0 * HH;
        const float* s2 = noiseD + (size_t)r0 * HH;
        #pragma unroll
        for (int i = 0; i < 6; ++i) {
            int idx = i*512 + tid;
            int row = idx / 96, t = idx - row*96;
            noiseTD[t*NSTR + row*2    ] = s1[idx];
            noiseTD[t*NSTR + row*2 + 1] = s2[idx];
        }
    }
    const float lam  = Lambda1[0];
    const float budH = Budget1[0] * (1.0f/96.0f);
    const float b3s  = b3[0];
    const float per_step = lam * 2.0f + budH;
    if (tid < HH) {
        float e  = __builtin_exp2f(-2.0f * (float)(95 - tid));
        float ft = 0.5f * (1.0f - e);
        float G  = 2.0f + ft;
        *(f32x4*)&tblLDS[tid*4] = f32x4{ft, G, 1.0f/G, lam*2.0f + budH*((float)tid + 2.0f)};
    }

    // ---- W2 -> fp16 B-frags: 4 n-tiles/wave, n-range = wid4*64..+63 ----
    f16x8 bfr[4][8];
    float b2v[4], w3v[4];
    #pragma unroll
    for (int tt = 0; tt < 4; ++tt) {
        const int n = wid4*64 + tt*16 + l16;
        const float* wrow = W2 + (size_t)n * 256;
        #pragma unroll
        for (int kc = 0; kc < 8; ++kc) {
            const int k0 = kc*32 + lq*8;
            f32x4 u0 = *(const f32x4*)(wrow + k0);
            f32x4 u1 = *(const f32x4*)(wrow + k0 + 4);
            f16x8 v;
            v[0]=(_Float16)u0[0]; v[1]=(_Float16)u0[1]; v[2]=(_Float16)u0[2]; v[3]=(_Float16)u0[3];
            v[4]=(_Float16)u1[0]; v[5]=(_Float16)u1[1]; v[6]=(_Float16)u1[2]; v[7]=(_Float16)u1[3];
            bfr[tt][kc] = v;
        }
        b2v[tt] = b2[n];
        w3v[tt] = W3[n];
    }

    // ---- W1 as MFMA A-frags (bias folded at k=6) ----
    f16x8 w1A[4];
    #pragma unroll
    for (int tt = 0; tt < 4; ++tt) {
        f16x8 w = {};
        if (lq == 0) {
            const int nn = wid4*64 + tt*16 + l16;
            #pragma unroll
            for (int j = 0; j < 6; ++j) w[j] = (_Float16)W1[nn*6 + j];
            w[6] = (_Float16)b1[nn];
        }
        w1A[tt] = w;
    }

    // h1 write: value (tt,r) -> k = wid4*64+tt*16+lq*4+r, m = l16
    const int h1wbase = (wid4*8 + (lq>>1))*OCT + l16*8 + (lq&1)*4;
    const int h1rbase = lq*OCT + l16*8;          // + kc*(4*OCT)

    SState st = { action_pre[rbase + l16], state_pre[rbase + l16],
                  per_step, 0.f, 0.f, 0.f };

    __syncthreads();   // staging complete

    // ---- prologue: P stages h1P(0) from featLDS ----
    if (!roleQ) {
        f32x4 f0 = *(const f32x4*)&featLDS[(0*RPB + rloc)*4];
        phaseA(h1P, f0, st, w1A, lq, h1wbase);
    }
    __syncthreads();   // h1P(0) ready

    #pragma unroll 1
    for (int t = 0; t < HH; ++t) {
        if (!roleQ) {
            // ---- P half-1: B(t) + C(t) -> partP ----
            f32x4 acc[4];
            #pragma unroll
            for (int tt = 0; tt < 4; ++tt) acc[tt] = f32x4{b2v[tt],b2v[tt],b2v[tt],b2v[tt]};
            #pragma unroll
            for (int kc = 0; kc < 8; ++kc) {
                f16x8 a = *(const f16x8*)&h1P[h1rbase + kc*(4*OCT)];
                #pragma unroll
                for (int tt = 0; tt < 4; ++tt)
                    acc[tt] = __builtin_amdgcn_mfma_f32_16x16x32_f16(a, bfr[tt][kc], acc[tt], 0, 0, 0);
            }
            #pragma unroll
            for (int r = 0; r < 4; ++r) {
                float s0 = fmaf(w3v[0], fmaxf(acc[0][r], 0.0f), w3v[1] * fmaxf(acc[1][r], 0.0f));
                float s1 = fmaf(w3v[2], fmaxf(acc[2][r], 0.0f), w3v[3] * fmaxf(acc[3][r], 0.0f));
                float v = s0 + s1;
                v = DPP_ADD(v, 0xB1); v = DPP_ADD(v, 0x4E);
                v = DPP_ADD(v, 0x124); v = DPP_ADD(v, 0x128);
                if (l16 == 0) partP[(lq*4 + r)*4 + wid4] = v;
            }
        } else {
            // ---- Q half-1: D(t-1) + A(t) ----
            if (t > 0) {
                f32x4 q  = *(const f32x4*)&partQ[l16*4];
                f32x4 tb = *(const f32x4*)&tblLDS[(t-1)*4];
                f32x2 nz = *(const f32x2*)&noiseTD[(t-1)*NSTR + rloc*2];
                float dem = featLDS[((t-1)*RPB + rloc)*4];
                float psum = (q[0] + q[1]) + (q[2] + q[3]);
                float aQ = scan_update(st, psum, dem, nz, tb,
                                       b3s, lam, per_step, false);
                if (wid4 == 0 && lane < 16) outLDS[(16 + lane)*OSTR + (t-1)] = aQ;
            }
            f32x4 fq = *(const f32x4*)&featLDS[(t*RPB + rloc)*4];
            phaseA(h1Q, fq, st, w1A, lq, h1wbase);
        }
        __syncthreads();   // partP(t) ready; h1Q(t) ready

        if (!roleQ) {
            // ---- P half-2: D(t) + A(t+1) ----
            f32x4 q  = *(const f32x4*)&partP[l16*4];
            f32x4 tb = *(const f32x4*)&tblLDS[t*4];
            f32x2 nz = *(const f32x2*)&noiseTD[t*NSTR + rloc*2];
            float dem = featLDS[(t*RPB + rloc)*4];
            float psum = (q[0] + q[1]) + (q[2] + q[3]);
            float aP = scan_update(st, psum, dem, nz, tb,
                                   b3s, lam, per_step, t == HH-1);
            if (wid4 == 0 && lane < 16) outLDS[lane*OSTR + t] = aP;
            if (t < HH-1) {
                f32x4 fn = *(const f32x4*)&featLDS[((t+1)*RPB + rloc)*4];
                phaseA(h1P, fn, st, w1A, lq, h1wbase);
            }
        } else {
            // ---- Q half-2: B(t) + C(t) -> partQ ----
            f32x4 acc[4];
            #pragma unroll
            for (int tt = 0; tt < 4; ++tt) acc[tt] = f32x4{b2v[tt],b2v[tt],b2v[tt],b2v[tt]};
            #pragma unroll
            for (int kc = 0; kc < 8; ++kc) {
                f16x8 a = *(const f16x8*)&h1Q[h1rbase + kc*(4*OCT)];
                #pragma unroll
                for (int tt = 0; tt < 4; ++tt)
                    acc[tt] = __builtin_amdgcn_mfma_f32_16x16x32_f16(a, bfr[tt][kc], acc[tt], 0, 0, 0);
            }
            #pragma unroll
            for (int r = 0; r < 4; ++r) {
                float s0 = fmaf(w3v[0], fmaxf(acc[0][r], 0.0f), w3v[1] * fmaxf(acc[1][r], 0.0f));
                float s1 = fmaf(w3v[2], fmaxf(acc[2][r], 0.0f), w3v[3] * fmaxf(acc[3][r], 0.0f));
                float v = s0 + s1;
                v = DPP_ADD(v, 0xB1); v = DPP_ADD(v, 0x4E);
                v = DPP_ADD(v, 0x124); v = DPP_ADD(v, 0x128);
                if (l16 == 0) partQ[(lq*4 + r)*4 + wid4] = v;
            }
        }
        __syncthreads();   // h1P(t+1) ready; partQ(t) ready
    }

    // ---- epilogue: Q: D(95) ----
    if (roleQ) {
        f32x4 q  = *(const f32x4*)&partQ[l16*4];
        f32x4 tb = *(const f32x4*)&tblLDS[(HH-1)*4];
        f32x2 nz = *(const f32x2*)&noiseTD[(HH-1)*NSTR + rloc*2];
        float dem = featLDS[((HH-1)*RPB + rloc)*4];
        float psum = (q[0] + q[1]) + (q[2] + q[3]);
        float aQ = scan_update(st, psum, dem, nz, tb,
                               b3s, lam, per_step, true);
        if (wid4 == 0 && lane < 16) outLDS[(16 + lane)*OSTR + (HH-1)] = aQ;
    }

    // ---- coalesced output dump: 32 rows x 96 = 3072 dwords, 512 threads ----
    __syncthreads();
    float* oslice = out + (size_t)r0 * HH;
    #pragma unroll
    for (int i = 0; i < 3; ++i) {
        int idx = (i*512 + tid) * 2;               // 3072 dwords total
        int row = idx / 96, c = idx - row*96;      // pairs never straddle rows (96 even)
        f32x2 v = { outLDS[row*OSTR + c], outLDS[row*OSTR + c + 1] };
        *(f32x2*)&oslice[idx] = v;
    }
}

extern "C" void kernel_launch(void* const* d_in, const int* in_sizes, int n_in,
                              void* d_out, int out_size, void* d_ws, size_t ws_size,
                              hipStream_t stream) {
    policy_scan_kernel<<<dim3(8192 / RPB), dim3(512), 0, stream>>>(
        (const float*)d_in[0],  // policy_in_c
        (const float*)d_in[1],  // trans_noise
        (const float*)d_in[2],  // demand_noise
        (const float*)d_in[3],  // action_pre
        (const float*)d_in[4],  // state_pre
        (const float*)d_in[5],  // Lambda
        (const float*)d_in[6],  // Budget
        (const float*)d_in[7],  // W1
        (const float*)d_in[8],  // b1
        (const float*)d_in[9],  // W2
        (const float*)d_in[10], // b2
        (const float*)d_in[11], // W3
        (const float*)d_in[12], // b3
        (float*)d_out);
}